// Round 1
// baseline (378.556 us; speedup 1.0000x reference)
//
#include <hip/hip_runtime.h>
#include <math.h>

// Problem constants (GNNObservationEncoder: 2-layer GAT, full graph)
#define Bc   8
#define Nc   1024
#define OBSc 64
#define HIDc 192
#define NHc  3
#define Dc   64
#define ALPHAc 0.2f
#define NEGVc  (-9e15f)

// ---------------------------------------------------------------------------
// proj_kernel: Wh[bh][n][d] = sum_i x[b][n][i] * W[h][i][d]; also emits
// s_i = Wh . a_l  and  s_j = Wh . a_r  per (bh, n).
// Grid: (N/16, B*NH), block 256. Thread (q=tid&15 -> d-quad, w=tid>>4 -> row).
// ---------------------------------------------------------------------------
template <int KIN>
__global__ __launch_bounds__(256) void proj_kernel(
    const float* __restrict__ xin,   // [B][N][KIN]
    const float* __restrict__ W,     // [NH][KIN][D]
    const float* __restrict__ a,     // [NH][2*D]
    float* __restrict__ Wh,          // [B*NH][N][D]
    float* __restrict__ si,          // [B*NH][N]
    float* __restrict__ sj)          // [B*NH][N]
{
    __shared__ float xs[16][KIN + 1];   // +1 pad: broadcast rows hit distinct banks
    __shared__ float Ws[KIN][Dc];

    const int tid  = threadIdx.x;
    const int bh   = blockIdx.y;           // 0..B*NH-1
    const int b    = bh / NHc;
    const int hh   = bh % NHc;
    const int row0 = blockIdx.x * 16;

    for (int e = tid; e < 16 * KIN; e += 256) {
        int r = e / KIN, c = e % KIN;
        xs[r][c] = xin[((size_t)b * Nc + row0 + r) * KIN + c];
    }
    for (int e = tid; e < KIN * Dc; e += 256) {
        ((float*)Ws)[e] = W[(size_t)hh * KIN * Dc + e];
    }
    __syncthreads();

    const int q = tid & 15;       // d0 = 4*q
    const int w = tid >> 4;       // local row 0..15
    float4 acc = {0.f, 0.f, 0.f, 0.f};
    for (int i = 0; i < KIN; ++i) {
        float xv = xs[w][i];                          // broadcast (padded stride)
        float4 wv = *(const float4*)&Ws[i][4 * q];    // b128, 2-way (free)
        acc.x += xv * wv.x; acc.y += xv * wv.y;
        acc.z += xv * wv.z; acc.w += xv * wv.w;
    }

    const int row = row0 + w;
    *(float4*)&Wh[((size_t)bh * Nc + row) * Dc + 4 * q] = acc;

    // s_i / s_j: dot over d (reduce across the 16 q-lanes of this row group)
    float4 al = *(const float4*)&a[hh * 2 * Dc + 4 * q];
    float4 ar = *(const float4*)&a[hh * 2 * Dc + Dc + 4 * q];
    float pi = acc.x * al.x + acc.y * al.y + acc.z * al.z + acc.w * al.w;
    float pj = acc.x * ar.x + acc.y * ar.y + acc.z * ar.z + acc.w * ar.w;
    for (int off = 8; off >= 1; off >>= 1) {
        pi += __shfl_xor(pi, off, 64);
        pj += __shfl_xor(pj, off, 64);
    }
    if (q == 0) {
        si[(size_t)bh * Nc + row] = pi;
        sj[(size_t)bh * Nc + row] = pj;
    }
}

// ---------------------------------------------------------------------------
// stats_kernel: per row (bh,i): m = max_j e_ij, iZ = 1/sum_j exp(e_ij - m)
// where e_ij = adj[i][j]>0 ? leaky(s_i + s_j) : NEG.  One wave per row.
// ---------------------------------------------------------------------------
__global__ __launch_bounds__(256) void stats_kernel(
    const float* __restrict__ si, const float* __restrict__ sj,
    const float* __restrict__ adj,
    float* __restrict__ mrow, float* __restrict__ izrow)
{
    const int row  = (blockIdx.x * 256 + threadIdx.x) >> 6;   // global wave id
    const int lane = threadIdx.x & 63;
    const int bh   = row >> 10;        // / N
    const int i    = row & (Nc - 1);

    const float s_i = si[row];
    const float* sjr  = sj + (size_t)bh * Nc;
    const float* adjr = adj + (size_t)i * Nc;

    float e[16];
    float mx = -INFINITY;
#pragma unroll
    for (int k = 0; k < 16; ++k) {
        int j = lane + 64 * k;
        float ee = s_i + sjr[j];
        ee = ee > 0.f ? ee : ALPHAc * ee;
        ee = adjr[j] > 0.f ? ee : NEGVc;
        e[k] = ee;
        mx = fmaxf(mx, ee);
    }
    for (int off = 32; off >= 1; off >>= 1) mx = fmaxf(mx, __shfl_xor(mx, off, 64));
    float sum = 0.f;
#pragma unroll
    for (int k = 0; k < 16; ++k) sum += __expf(e[k] - mx);
    for (int off = 32; off >= 1; off >>= 1) sum += __shfl_xor(sum, off, 64);
    if (lane == 0) { mrow[row] = mx; izrow[row] = 1.0f / sum; }
}

// ---------------------------------------------------------------------------
// aggr_kernel: out[b][row][hh*D + d] = sum_j P_rj * Wh[bh][j][d]
// P computed on the fly from (s_i, s_j, m, iZ, adj). 32 rows per block.
// DO_ELU applies the inter-layer ELU (layer-1 output feeds layer 2).
// ---------------------------------------------------------------------------
template <bool DO_ELU>
__global__ __launch_bounds__(256) void aggr_kernel(
    const float* __restrict__ Wh,    // [B*NH][N][D]
    const float* __restrict__ si,
    const float* __restrict__ sj,
    const float* __restrict__ mrow,
    const float* __restrict__ izrow,
    const float* __restrict__ adj,
    float* __restrict__ out)         // [B][N][HID]
{
    __shared__ float Whs[64][Dc];        // 16 KB
    __shared__ float ps[32][65];         // 8.3 KB (+1 pad: broadcast rows)
    __shared__ float s_i_s[32], m_s[32], iz_s[32];

    const int tid  = threadIdx.x;
    const int bh   = blockIdx.y;
    const int b    = bh / NHc;
    const int hh   = bh % NHc;
    const int row0 = blockIdx.x * 32;

    if (tid < 32) {
        size_t g = (size_t)bh * Nc + row0 + tid;
        s_i_s[tid] = si[g];
        m_s[tid]   = mrow[g];
        iz_s[tid]  = izrow[g];
    }
    __syncthreads();

    const int q = tid & 15;        // d0 = 4*q
    const int w = tid >> 4;        // rows w and w+16
    float4 acc0 = {0.f, 0.f, 0.f, 0.f};
    float4 acc1 = {0.f, 0.f, 0.f, 0.f};

    const float* Whbh = Wh + (size_t)bh * Nc * Dc;
    const float* sjr  = sj + (size_t)bh * Nc;

    for (int jt = 0; jt < Nc; jt += 64) {
        // stage Wh j-tile (coalesced: [n][d] row-major slab)
        for (int e = tid; e < 64 * Dc; e += 256) {
            ((float*)Whs)[e] = Whbh[(size_t)jt * Dc + e];
        }
        // compute P tile: thread covers (r = (tid>>6)+4k, j = tid&63)
        {
            const int j  = tid & 63;
            const int rr = tid >> 6;
            const float sjv = sjr[jt + j];
#pragma unroll
            for (int k = 0; k < 8; ++k) {
                int r = rr + 4 * k;
                float ee = s_i_s[r] + sjv;
                ee = ee > 0.f ? ee : ALPHAc * ee;
                float av = adj[(size_t)(row0 + r) * Nc + jt + j];
                ee = av > 0.f ? ee : NEGVc;
                ps[r][j] = __expf(ee - m_s[r]) * iz_s[r];
            }
        }
        __syncthreads();
#pragma unroll 4
        for (int j = 0; j < 64; ++j) {
            float4 wv = *(const float4*)&Whs[j][4 * q];  // b128
            float p0 = ps[w][j];                         // broadcast
            float p1 = ps[w + 16][j];                    // broadcast
            acc0.x += p0 * wv.x; acc0.y += p0 * wv.y;
            acc0.z += p0 * wv.z; acc0.w += p0 * wv.w;
            acc1.x += p1 * wv.x; acc1.y += p1 * wv.y;
            acc1.z += p1 * wv.z; acc1.w += p1 * wv.w;
        }
        __syncthreads();
    }

    float4 vals[2] = {acc0, acc1};
    const int rloc[2] = {w, w + 16};
#pragma unroll
    for (int t = 0; t < 2; ++t) {
        float4 v = vals[t];
        if (DO_ELU) {
            v.x = v.x > 0.f ? v.x : expm1f(v.x);
            v.y = v.y > 0.f ? v.y : expm1f(v.y);
            v.z = v.z > 0.f ? v.z : expm1f(v.z);
            v.w = v.w > 0.f ? v.w : expm1f(v.w);
        }
        *(float4*)&out[((size_t)b * Nc + row0 + rloc[t]) * HIDc + hh * Dc + 4 * q] = v;
    }
}

// ---------------------------------------------------------------------------
extern "C" void kernel_launch(void* const* d_in, const int* in_sizes, int n_in,
                              void* d_out, int out_size, void* d_ws, size_t ws_size,
                              hipStream_t stream) {
    const float* h_in = (const float*)d_in[0];   // (B,N,OBS)
    const float* adj  = (const float*)d_in[1];   // (N,N)
    const float* W1   = (const float*)d_in[2];   // (NH,OBS,D)
    const float* a1   = (const float*)d_in[3];   // (NH,2D)
    const float* W2   = (const float*)d_in[4];   // (NH,HID,D)
    const float* a2   = (const float*)d_in[5];   // (NH,2D)
    float* out = (float*)d_out;

    // Workspace layout (floats). Wh buffer reused across layers.
    float* ws   = (float*)d_ws;
    const size_t nWh = (size_t)Bc * NHc * Nc * Dc;   // 1,572,864
    const size_t nX  = (size_t)Bc * Nc * HIDc;       // 1,572,864
    const size_t nR  = (size_t)Bc * NHc * Nc;        // 24,576
    float* Whb = ws;
    float* x   = Whb + nWh;
    float* si  = x + nX;
    float* sj  = si + nR;
    float* mr  = sj + nR;
    float* iz  = mr + nR;
    // total: 3,243,008 floats = 12.97 MB

    dim3 projGrid(Nc / 16, Bc * NHc);
    dim3 aggrGrid(Nc / 32, Bc * NHc);
    int statsBlocks = (Bc * NHc * Nc) / 4;   // one wave per row, 4 waves/block

    // ----- Layer 1 -----
    proj_kernel<OBSc><<<projGrid, 256, 0, stream>>>(h_in, W1, a1, Whb, si, sj);
    stats_kernel<<<statsBlocks, 256, 0, stream>>>(si, sj, adj, mr, iz);
    aggr_kernel<true><<<aggrGrid, 256, 0, stream>>>(Whb, si, sj, mr, iz, adj, x);

    // ----- Layer 2 -----
    proj_kernel<HIDc><<<projGrid, 256, 0, stream>>>(x, W2, a2, Whb, si, sj);
    stats_kernel<<<statsBlocks, 256, 0, stream>>>(si, sj, adj, mr, iz);
    aggr_kernel<false><<<aggrGrid, 256, 0, stream>>>(Whb, si, sj, mr, iz, adj, out);
}

// Round 2
// 185.643 us; speedup vs baseline: 2.0392x; 2.0392x over previous
//
#include <hip/hip_runtime.h>
#include <math.h>

// Problem constants (GNNObservationEncoder: 2-layer GAT, full graph)
#define Bc   8
#define Nc   1024
#define OBSc 64
#define HIDc 192
#define NHc  3
#define Dc   64
#define ALPHAc 0.2f
#define NEGVc  (-9e15f)

typedef __attribute__((ext_vector_type(8))) _Float16 half8;
typedef __attribute__((ext_vector_type(4))) float floatx4;

// ---------------------------------------------------------------------------
// proj_kernel: Wh = x @ W per head. Writes TRANSPOSED fp16 WhT[bh][d][n]
// (feeds aggr's MFMA B-fragments), plus s_i / s_j scores (fp32).
// Grid: (N/16, B*NH), block 256. Thread (q=tid&15 -> d-quad, w=tid>>4 -> row).
// ---------------------------------------------------------------------------
template <int KIN>
__global__ __launch_bounds__(256) void proj_kernel(
    const float* __restrict__ xin,   // [B][N][KIN]
    const float* __restrict__ W,     // [NH][KIN][D]
    const float* __restrict__ a,     // [NH][2*D]
    _Float16* __restrict__ WhT,      // [B*NH][D][N] fp16 (transposed)
    float* __restrict__ si,          // [B*NH][N]
    float* __restrict__ sj)          // [B*NH][N]
{
    __shared__ float xs[16][KIN + 1];
    __shared__ float Ws[KIN][Dc];

    const int tid  = threadIdx.x;
    const int bh   = blockIdx.y;
    const int b    = bh / NHc;
    const int hh   = bh % NHc;
    const int row0 = blockIdx.x * 16;

    for (int e = tid; e < 16 * KIN; e += 256) {
        int r = e / KIN, c = e % KIN;
        xs[r][c] = xin[((size_t)b * Nc + row0 + r) * KIN + c];
    }
    for (int e = tid; e < KIN * Dc; e += 256) {
        ((float*)Ws)[e] = W[(size_t)hh * KIN * Dc + e];
    }
    __syncthreads();

    const int q = tid & 15;       // d0 = 4*q
    const int w = tid >> 4;       // local row 0..15
    float4 acc = {0.f, 0.f, 0.f, 0.f};
    for (int i = 0; i < KIN; ++i) {
        float xv = xs[w][i];
        float4 wv = *(const float4*)&Ws[i][4 * q];
        acc.x += xv * wv.x; acc.y += xv * wv.y;
        acc.z += xv * wv.z; acc.w += xv * wv.w;
    }

    const int row = row0 + w;
    // transposed fp16 store: WhT[bh][4q+t][row]
    _Float16* wt = WhT + ((size_t)bh * Dc + 4 * q) * Nc + row;
    wt[0]          = (_Float16)acc.x;
    wt[Nc]         = (_Float16)acc.y;
    wt[2 * Nc]     = (_Float16)acc.z;
    wt[3 * Nc]     = (_Float16)acc.w;

    float4 al = *(const float4*)&a[hh * 2 * Dc + 4 * q];
    float4 ar = *(const float4*)&a[hh * 2 * Dc + Dc + 4 * q];
    float pi = acc.x * al.x + acc.y * al.y + acc.z * al.z + acc.w * al.w;
    float pj = acc.x * ar.x + acc.y * ar.y + acc.z * ar.z + acc.w * ar.w;
    for (int off = 8; off >= 1; off >>= 1) {
        pi += __shfl_xor(pi, off, 64);
        pj += __shfl_xor(pj, off, 64);
    }
    if (q == 0) {
        si[(size_t)bh * Nc + row] = pi;
        sj[(size_t)bh * Nc + row] = pj;
    }
}

// ---------------------------------------------------------------------------
// stats_kernel: per row (bh,i): m = max_j e_ij, iZ = 1/sum_j exp(e_ij - m).
// One wave per row.
// ---------------------------------------------------------------------------
__global__ __launch_bounds__(256) void stats_kernel(
    const float* __restrict__ si, const float* __restrict__ sj,
    const float* __restrict__ adj,
    float* __restrict__ mrow, float* __restrict__ izrow)
{
    const int row  = (blockIdx.x * 256 + threadIdx.x) >> 6;
    const int lane = threadIdx.x & 63;
    const int bh   = row >> 10;
    const int i    = row & (Nc - 1);

    const float s_i = si[row];
    const float* sjr  = sj + (size_t)bh * Nc;
    const float* adjr = adj + (size_t)i * Nc;

    float e[16];
    float mx = -INFINITY;
#pragma unroll
    for (int k = 0; k < 16; ++k) {
        int j = lane + 64 * k;
        float ee = s_i + sjr[j];
        ee = ee > 0.f ? ee : ALPHAc * ee;
        ee = adjr[j] > 0.f ? ee : NEGVc;
        e[k] = ee;
        mx = fmaxf(mx, ee);
    }
    for (int off = 32; off >= 1; off >>= 1) mx = fmaxf(mx, __shfl_xor(mx, off, 64));
    float sum = 0.f;
#pragma unroll
    for (int k = 0; k < 16; ++k) sum += __expf(e[k] - mx);
    for (int off = 32; off >= 1; off >>= 1) sum += __shfl_xor(sum, off, 64);
    if (lane == 0) { mrow[row] = mx; izrow[row] = 1.0f / sum; }
}

// ---------------------------------------------------------------------------
// aggr_kernel (MFMA): out[b][row][hh*D+d] = iZ_row * sum_j exp(e_rj - m_r) * Wh[j][d]
// Block: 32 rows x 64 d, one bh; K=1024 in 64-j tiles. 4 waves:
//   wave w: m-block = (w&1)*16, d-block = (w>>1)*32 (two 16-wide n-tiles).
// P tile computed on the fly (fp32 exp) -> fp16 LDS; Wh staged fp16 from WhT.
// ---------------------------------------------------------------------------
template <bool DO_ELU>
__global__ __launch_bounds__(256) void aggr_kernel(
    const _Float16* __restrict__ WhT,  // [B*NH][D][N] fp16
    const float* __restrict__ si,
    const float* __restrict__ sj,
    const float* __restrict__ mrow,
    const float* __restrict__ izrow,
    const float* __restrict__ adj,
    float* __restrict__ out)           // [B][N][HID]
{
    __shared__ _Float16 Whs[Dc][72];   // [d][j], rows padded to 144 B (9x16B)
    __shared__ _Float16 Ps[32][72];    // [r][j]
    __shared__ float s_i_s[32], m_s[32], iz_s[32];

    const int tid  = threadIdx.x;
    const int bh   = blockIdx.y;
    const int b    = bh / NHc;
    const int hh   = bh % NHc;
    const int row0 = blockIdx.x * 32;

    if (tid < 32) {
        size_t g = (size_t)bh * Nc + row0 + tid;
        s_i_s[tid] = si[g];
        m_s[tid]   = mrow[g];
        iz_s[tid]  = izrow[g];
    }
    __syncthreads();

    const int lane = tid & 63;
    const int wv   = tid >> 6;
    const int mblk = (wv & 1) * 16;
    const int dblk = (wv >> 1) * 32;
    const int fr   = lane & 15;    // fragment row/col
    const int fq   = lane >> 4;    // quad

    // P-compute coords: 2 consecutive j per thread, 8 rows strided by 8
    const int jj0  = (tid & 31) * 2;
    const int rr   = tid >> 5;

    floatx4 acc0 = {0.f, 0.f, 0.f, 0.f};
    floatx4 acc1 = {0.f, 0.f, 0.f, 0.f};

    const _Float16* WhTbh = WhT + (size_t)bh * Dc * Nc;
    const float* sjr = sj + (size_t)bh * Nc;

    for (int jt = 0; jt < Nc; jt += 64) {
        // ---- stage Wh j-tile: Whs[d][0..63] from WhT[bh][d][jt..jt+63]
        for (int e = tid; e < 512; e += 256) {
            int d = e >> 3, ch = e & 7;
            *(uint4*)&Whs[d][ch * 8] =
                *(const uint4*)&WhTbh[(size_t)d * Nc + jt + ch * 8];
        }
        // ---- compute P tile (fp32 -> fp16)
        {
            float2 sjv = *(const float2*)&sjr[jt + jj0];
#pragma unroll
            for (int k = 0; k < 4; ++k) {
                int r = rr + 8 * k;
                float2 av = *(const float2*)&adj[(size_t)(row0 + r) * Nc + jt + jj0];
                float e0 = s_i_s[r] + sjv.x;
                float e1 = s_i_s[r] + sjv.y;
                e0 = e0 > 0.f ? e0 : ALPHAc * e0;
                e1 = e1 > 0.f ? e1 : ALPHAc * e1;
                e0 = av.x > 0.f ? e0 : NEGVc;
                e1 = av.y > 0.f ? e1 : NEGVc;
                float p0 = __expf(e0 - m_s[r]);
                float p1 = __expf(e1 - m_s[r]);
                union { unsigned int u; _Float16 h[2]; } pk;
                pk.h[0] = (_Float16)p0;
                pk.h[1] = (_Float16)p1;
                *(unsigned int*)&Ps[r][jj0] = pk.u;
            }
        }
        __syncthreads();
        // ---- MFMA: 2 k-steps of 32
#pragma unroll
        for (int ks = 0; ks < 2; ++ks) {
            int k0 = ks * 32 + fq * 8;
            half8 afrag = *(const half8*)&Ps[mblk + fr][k0];
            half8 b0    = *(const half8*)&Whs[dblk + fr][k0];
            half8 b1    = *(const half8*)&Whs[dblk + 16 + fr][k0];
            acc0 = __builtin_amdgcn_mfma_f32_16x16x32_f16(afrag, b0, acc0, 0, 0, 0);
            acc1 = __builtin_amdgcn_mfma_f32_16x16x32_f16(afrag, b1, acc1, 0, 0, 0);
        }
        __syncthreads();
    }

    // ---- epilogue: scale by iZ, optional ELU, store
#pragma unroll
    for (int nt = 0; nt < 2; ++nt) {
        floatx4 acc = nt ? acc1 : acc0;
        int dcol = dblk + nt * 16 + fr;
#pragma unroll
        for (int reg = 0; reg < 4; ++reg) {
            int mr = mblk + fq * 4 + reg;
            float v = acc[reg] * iz_s[mr];
            if (DO_ELU) v = v > 0.f ? v : expm1f(v);
            out[((size_t)b * Nc + row0 + mr) * HIDc + hh * Dc + dcol] = v;
        }
    }
}

// ---------------------------------------------------------------------------
extern "C" void kernel_launch(void* const* d_in, const int* in_sizes, int n_in,
                              void* d_out, int out_size, void* d_ws, size_t ws_size,
                              hipStream_t stream) {
    const float* h_in = (const float*)d_in[0];   // (B,N,OBS)
    const float* adj  = (const float*)d_in[1];   // (N,N)
    const float* W1   = (const float*)d_in[2];   // (NH,OBS,D)
    const float* a1   = (const float*)d_in[3];   // (NH,2D)
    const float* W2   = (const float*)d_in[4];   // (NH,HID,D)
    const float* a2   = (const float*)d_in[5];   // (NH,2D)
    float* out = (float*)d_out;

    float* ws = (float*)d_ws;
    const size_t nWhT_f = (size_t)Bc * NHc * Dc * Nc / 2;  // fp16 in float slots
    const size_t nX  = (size_t)Bc * Nc * HIDc;
    const size_t nR  = (size_t)Bc * NHc * Nc;
    _Float16* WhT = (_Float16*)ws;
    float* x   = ws + nWhT_f;
    float* si  = x + nX;
    float* sj  = si + nR;
    float* mr  = sj + nR;
    float* iz  = mr + nR;
    // total: ~9.8 MB

    dim3 projGrid(Nc / 16, Bc * NHc);
    dim3 aggrGrid(Nc / 32, Bc * NHc);
    int statsBlocks = (Bc * NHc * Nc) / 4;

    // ----- Layer 1 -----
    proj_kernel<OBSc><<<projGrid, 256, 0, stream>>>(h_in, W1, a1, WhT, si, sj);
    stats_kernel<<<statsBlocks, 256, 0, stream>>>(si, sj, adj, mr, iz);
    aggr_kernel<true><<<aggrGrid, 256, 0, stream>>>(WhT, si, sj, mr, iz, adj, x);

    // ----- Layer 2 -----
    proj_kernel<HIDc><<<projGrid, 256, 0, stream>>>(x, W2, a2, WhT, si, sj);
    stats_kernel<<<statsBlocks, 256, 0, stream>>>(si, sj, adj, mr, iz);
    aggr_kernel<false><<<aggrGrid, 256, 0, stream>>>(WhT, si, sj, mr, iz, adj, out);
}

// Round 3
// 167.050 us; speedup vs baseline: 2.2661x; 1.1113x over previous
//
#include <hip/hip_runtime.h>
#include <math.h>

// Problem constants (GNNObservationEncoder: 2-layer GAT, full graph)
#define Bc   8
#define Nc   1024
#define OBSc 64
#define HIDc 192
#define NHc  3
#define Dc   64
#define ALPHAc 0.2f
#define NEGVc  (-9e15f)

typedef __attribute__((ext_vector_type(8))) _Float16 half8;
typedef __attribute__((ext_vector_type(4))) float floatx4;

// ---------------------------------------------------------------------------
// proj_kernel (MFMA): Wh = x @ W per head, fp16 MFMA 16x16x32.
//   A-frags: direct global loads of x rows (fp32 input converts on the fly).
//   B: W^T staged to LDS fp16 (transpose during staging; once per block).
// Emits: WhT[bh][d][n] fp16 (via LDS transpose), s_i / s_j fp32 (fused dot+reduce).
// Block: 32 rows x 64 d. Waves: mblk=(w&1)*16, nhalf=(w>>1)*32. Grid (N/32, B*NH).
// ---------------------------------------------------------------------------
template <int KIN, bool XF32>
__global__ __launch_bounds__(256) void proj_kernel(
    const void* __restrict__ xin_,   // [B][N][KIN] fp32 (XF32) or fp16
    const float* __restrict__ W,     // [NH][KIN][D] fp32
    const float* __restrict__ a,     // [NH][2*D] fp32
    _Float16* __restrict__ WhT,      // [B*NH][D][N] fp16
    float* __restrict__ si,          // [B*NH][N]
    float* __restrict__ sj)          // [B*NH][N]
{
    __shared__ union {
        _Float16 Bs[64][KIN + 8];    // [d][k] = W^T, row stride 16B-aligned
        _Float16 Ts[64][40];         // [d][local row] transpose staging
    } u;
    __shared__ float spsA_i[32], spsA_j[32], spsB_i[32], spsB_j[32];

    const int tid  = threadIdx.x;
    const int bh   = blockIdx.y;
    const int b    = bh / NHc;
    const int hh   = bh % NHc;
    const int row0 = blockIdx.x * 32;

    // stage W^T -> Bs (fp32 -> fp16, transposed). Coalesced global read.
    for (int e = tid; e < KIN * 64; e += 256) {
        int k = e >> 6, d = e & 63;
        u.Bs[d][k] = (_Float16)W[(size_t)hh * KIN * 64 + e];
    }
    __syncthreads();

    const int lane  = tid & 63, wv = tid >> 6;
    const int mblk  = (wv & 1) * 16;
    const int nhalf = (wv >> 1) * 32;
    const int fr    = lane & 15, fq = lane >> 4;

    floatx4 acc0 = {0.f, 0.f, 0.f, 0.f};
    floatx4 acc1 = {0.f, 0.f, 0.f, 0.f};
    const int row = row0 + mblk + fr;

#pragma unroll
    for (int ks = 0; ks < KIN / 32; ++ks) {
        const int k0 = ks * 32 + fq * 8;
        half8 af;
        if (XF32) {
            const float* xr = (const float*)xin_ + ((size_t)b * Nc + row) * KIN + k0;
            float4 u0 = *(const float4*)xr;
            float4 u1 = *(const float4*)(xr + 4);
            af[0] = (_Float16)u0.x; af[1] = (_Float16)u0.y;
            af[2] = (_Float16)u0.z; af[3] = (_Float16)u0.w;
            af[4] = (_Float16)u1.x; af[5] = (_Float16)u1.y;
            af[6] = (_Float16)u1.z; af[7] = (_Float16)u1.w;
        } else {
            af = *(const half8*)((const _Float16*)xin_ + ((size_t)b * Nc + row) * KIN + k0);
        }
        half8 b0 = *(const half8*)&u.Bs[nhalf + fr][k0];
        half8 b1 = *(const half8*)&u.Bs[nhalf + 16 + fr][k0];
        acc0 = __builtin_amdgcn_mfma_f32_16x16x32_f16(af, b0, acc0, 0, 0, 0);
        acc1 = __builtin_amdgcn_mfma_f32_16x16x32_f16(af, b1, acc1, 0, 0, 0);
    }

    // fused s_i / s_j: per-lane partial over this wave's 32 cols, reduce over fr
    const float al0 = a[hh * 2 * Dc + nhalf + fr];
    const float al1 = a[hh * 2 * Dc + nhalf + 16 + fr];
    const float ar0 = a[hh * 2 * Dc + Dc + nhalf + fr];
    const float ar1 = a[hh * 2 * Dc + Dc + nhalf + 16 + fr];
    float pi[4], pj[4];
#pragma unroll
    for (int r = 0; r < 4; ++r) {
        pi[r] = acc0[r] * al0 + acc1[r] * al1;
        pj[r] = acc0[r] * ar0 + acc1[r] * ar1;
        for (int off = 8; off >= 1; off >>= 1) {
            pi[r] += __shfl_xor(pi[r], off, 64);
            pj[r] += __shfl_xor(pj[r], off, 64);
        }
    }
    if (fr == 0) {
#pragma unroll
        for (int r = 0; r < 4; ++r) {
            int lr = mblk + fq * 4 + r;
            if (nhalf == 0) { spsA_i[lr] = pi[r]; spsA_j[lr] = pj[r]; }
            else            { spsB_i[lr] = pi[r]; spsB_j[lr] = pj[r]; }
        }
    }
    __syncthreads();   // Bs reads complete; sps complete
    if (tid < 32) {
        size_t g = (size_t)bh * Nc + row0 + tid;
        si[g] = spsA_i[tid] + spsB_i[tid];
        sj[g] = spsA_j[tid] + spsB_j[tid];
    }

    // Wh -> fp16 transposed through LDS (u32 pair writes: 2-way, free)
#pragma unroll
    for (int nt = 0; nt < 2; ++nt) {
        const int d = nhalf + nt * 16 + fr;
        floatx4 acc = nt ? acc1 : acc0;
#pragma unroll
        for (int p = 0; p < 2; ++p) {
            union { unsigned int w; _Float16 h[2]; } pk;
            pk.h[0] = (_Float16)acc[2 * p];
            pk.h[1] = (_Float16)acc[2 * p + 1];
            *(unsigned int*)&u.Ts[d][mblk + fq * 4 + 2 * p] = pk.w;
        }
    }
    __syncthreads();
    {   // 64 d-rows x 32 halves = 256 uint4, one per thread, coalesced store
        const int d = tid >> 2, ch = tid & 3;
        uint4 v = *(const uint4*)&u.Ts[d][ch * 8];
        *(uint4*)&WhT[(((size_t)bh * Dc + d) << 10) + row0 + ch * 8] = v;
    }
}

// ---------------------------------------------------------------------------
// stats_kernel: per row (bh,i): m = max_j e_ij, iZ = 1/sum_j exp(e_ij - m).
// One wave per row. PACK: also pack adj>0 into bitmask (bh==0 waves write).
// USEBITS: read bitmask instead of raw fp32 adj.
// ---------------------------------------------------------------------------
template <bool PACK, bool USEBITS>
__global__ __launch_bounds__(256) void stats_kernel(
    const float* __restrict__ si, const float* __restrict__ sj,
    const float* __restrict__ adj,
    unsigned long long* __restrict__ adjb,   // [N][16] bit l of word g = adj[i][g*64+l]>0
    float* __restrict__ mrow, float* __restrict__ izrow)
{
    const int gw   = (blockIdx.x * 256 + threadIdx.x) >> 6;
    const int lane = threadIdx.x & 63;
    const int bh   = gw >> 10;
    const int i    = gw & (Nc - 1);

    const float s_i = si[gw];
    const float* sjr = sj + (size_t)bh * Nc;

    float e[16];
    float mx = -INFINITY;
    unsigned long long myword = 0;
#pragma unroll
    for (int k = 0; k < 16; ++k) {
        int j = lane + 64 * k;
        float ee = s_i + sjr[j];
        ee = ee > 0.f ? ee : ALPHAc * ee;
        bool conn;
        if (USEBITS) {
            conn = (adjb[(size_t)i * 16 + k] >> lane) & 1;
        } else {
            conn = adj[(size_t)i * Nc + j] > 0.f;
        }
        if (PACK) {
            unsigned long long bal = __ballot(conn);
            if (lane == k) myword = bal;
        }
        ee = conn ? ee : NEGVc;
        e[k] = ee;
        mx = fmaxf(mx, ee);
    }
    if (PACK && bh == 0 && lane < 16) adjb[(size_t)i * 16 + lane] = myword;

    for (int off = 32; off >= 1; off >>= 1) mx = fmaxf(mx, __shfl_xor(mx, off, 64));
    float sum = 0.f;
#pragma unroll
    for (int k = 0; k < 16; ++k) sum += __expf(e[k] - mx);
    for (int off = 32; off >= 1; off >>= 1) sum += __shfl_xor(sum, off, 64);
    if (lane == 0) { mrow[gw] = mx; izrow[gw] = 1.0f / sum; }
}

// ---------------------------------------------------------------------------
// aggr_kernel (MFMA): out[row][hh*D+d] = iZ_r * sum_j exp(e_rj - m_r) * Wh[j][d]
// Block: 16 rows x 64 d; j-tiles of 128. P -> LDS fp16; B-frags DIRECT from
// global WhT (L2-resident, no LDS stage, no staging drain at the barrier).
// Wave w covers d-block w*16. Grid (N/16, B*NH) = 1536 blocks.
// ---------------------------------------------------------------------------
template <bool DO_ELU, typename OutT>
__global__ __launch_bounds__(256) void aggr_kernel(
    const _Float16* __restrict__ WhT,  // [B*NH][D][N] fp16
    const float* __restrict__ si,
    const float* __restrict__ sj,
    const float* __restrict__ mrow,
    const float* __restrict__ izrow,
    const unsigned long long* __restrict__ adjb,
    OutT* __restrict__ out)            // [B][N][HID] fp16 (layer1) / fp32 (layer2)
{
    __shared__ _Float16 Ps[16][136];   // row stride 272 B (17x16B, b128-aligned)
    __shared__ float s_i_s[16], m_s[16], iz_s[16];

    const int tid  = threadIdx.x;
    const int bh   = blockIdx.y;
    const int b    = bh / NHc;
    const int hh   = bh % NHc;
    const int row0 = blockIdx.x * 16;

    if (tid < 16) {
        size_t g = (size_t)bh * Nc + row0 + tid;
        s_i_s[tid] = si[g];
        m_s[tid]   = mrow[g];
        iz_s[tid]  = izrow[g];
    }
    __syncthreads();

    const int lane = tid & 63, wv = tid >> 6;
    const int dblk = wv * 16;
    const int fr   = lane & 15, fq = lane >> 4;
    const int jj0  = (tid & 63) * 2;     // P-compute: col pair
    const int rr   = tid >> 6;           // P-compute: row base (stride 4)

    floatx4 acc = {0.f, 0.f, 0.f, 0.f};
    const _Float16* WhTd = WhT + (((size_t)bh * Dc + dblk + fr) << 10);
    const float* sjr = sj + (size_t)bh * Nc;

    for (int jt = 0; jt < Nc; jt += 128) {
        // ---- P tile (16 x 128): 8 elements per thread
        float2 sjv = *(const float2*)&sjr[jt + jj0];
        const int g   = (jt + jj0) >> 6;
        const int bsh = jj0 & 63;
#pragma unroll
        for (int k = 0; k < 4; ++k) {
            int r = rr + 4 * k;
            unsigned long long w = adjb[(size_t)(row0 + r) * 16 + g];
            float e0 = s_i_s[r] + sjv.x;
            float e1 = s_i_s[r] + sjv.y;
            e0 = e0 > 0.f ? e0 : ALPHAc * e0;
            e1 = e1 > 0.f ? e1 : ALPHAc * e1;
            e0 = ((w >> bsh) & 1)       ? e0 : NEGVc;
            e1 = ((w >> (bsh + 1)) & 1) ? e1 : NEGVc;
            union { unsigned int u32; _Float16 h[2]; } pk;
            pk.h[0] = (_Float16)__expf(e0 - m_s[r]);
            pk.h[1] = (_Float16)__expf(e1 - m_s[r]);
            *(unsigned int*)&Ps[r][jj0] = pk.u32;   // consecutive words: conflict-free
        }
        __syncthreads();
        // ---- MFMA: A from Ps (LDS), B direct from global WhT
#pragma unroll
        for (int ks = 0; ks < 4; ++ks) {
            const int k0 = ks * 32 + fq * 8;
            half8 af = *(const half8*)&Ps[fr][k0];
            half8 bf = *(const half8*)&WhTd[jt + k0];
            acc = __builtin_amdgcn_mfma_f32_16x16x32_f16(af, bf, acc, 0, 0, 0);
        }
        __syncthreads();
    }

    // ---- epilogue: scale by iZ, optional ELU, store (C/D: col=fr, row=fq*4+reg)
    const int dcol = dblk + fr;
#pragma unroll
    for (int reg = 0; reg < 4; ++reg) {
        const int mr = fq * 4 + reg;
        float v = acc[reg] * iz_s[mr];
        if (DO_ELU) v = v > 0.f ? v : expm1f(v);
        out[((size_t)b * Nc + row0 + mr) * HIDc + hh * Dc + dcol] = (OutT)v;
    }
}

// ---------------------------------------------------------------------------
extern "C" void kernel_launch(void* const* d_in, const int* in_sizes, int n_in,
                              void* d_out, int out_size, void* d_ws, size_t ws_size,
                              hipStream_t stream) {
    const float* h_in = (const float*)d_in[0];   // (B,N,OBS)
    const float* adj  = (const float*)d_in[1];   // (N,N)
    const float* W1   = (const float*)d_in[2];   // (NH,OBS,D)
    const float* a1   = (const float*)d_in[3];   // (NH,2D)
    const float* W2   = (const float*)d_in[4];   // (NH,HID,D)
    const float* a2   = (const float*)d_in[5];   // (NH,2D)
    float* out = (float*)d_out;

    // workspace layout (16B-aligned chunks)
    float* ws = (float*)d_ws;
    const size_t nWhT_f = (size_t)Bc * NHc * Dc * Nc / 2;   // 786432 floats
    const size_t nXh_f  = (size_t)Bc * Nc * HIDc / 2;       // 786432 floats
    const size_t nAb_f  = (size_t)Nc * 16 * 2;              // 32768 floats
    const size_t nR     = (size_t)Bc * NHc * Nc;            // 24576
    _Float16* WhT = (_Float16*)ws;
    _Float16* xh  = (_Float16*)(ws + nWhT_f);
    unsigned long long* adjb = (unsigned long long*)(ws + nWhT_f + nXh_f);
    float* si = ws + nWhT_f + nXh_f + nAb_f;
    float* sj = si + nR;
    float* mr = sj + nR;
    float* iz = mr + nR;
    // total ~6.8 MB

    dim3 projGrid(Nc / 32, Bc * NHc);    // 32 x 24
    dim3 aggrGrid(Nc / 16, Bc * NHc);    // 64 x 24
    int statsBlocks = (Bc * NHc * Nc) / 4;

    // ----- Layer 1 -----
    proj_kernel<OBSc, true><<<projGrid, 256, 0, stream>>>(h_in, W1, a1, WhT, si, sj);
    stats_kernel<true, false><<<statsBlocks, 256, 0, stream>>>(si, sj, adj, adjb, mr, iz);
    aggr_kernel<true, _Float16><<<aggrGrid, 256, 0, stream>>>(WhT, si, sj, mr, iz, adjb, xh);

    // ----- Layer 2 -----
    proj_kernel<HIDc, false><<<projGrid, 256, 0, stream>>>(xh, W2, a2, WhT, si, sj);
    stats_kernel<false, true><<<statsBlocks, 256, 0, stream>>>(si, sj, adj, adjb, mr, iz);
    aggr_kernel<false, float><<<aggrGrid, 256, 0, stream>>>(WhT, si, sj, mr, iz, adjb, out);
}

// Round 4
// 161.145 us; speedup vs baseline: 2.3492x; 1.0366x over previous
//
#include <hip/hip_runtime.h>
#include <math.h>

// Problem constants (GNNObservationEncoder: 2-layer GAT, full graph)
#define Bc   8
#define Nc   1024
#define OBSc 64
#define HIDc 192
#define NHc  3
#define Dc   64
#define ALPHAc 0.2f
#define NEGVc  (-9e15f)

typedef __attribute__((ext_vector_type(8))) _Float16 half8;
typedef __attribute__((ext_vector_type(4))) float floatx4;

// monotone float->uint encoding for atomicMax-based float max
__device__ __forceinline__ unsigned int enc_f32(float f) {
    unsigned int u = __float_as_uint(f);
    return (u & 0x80000000u) ? ~u : (u | 0x80000000u);
}
__device__ __forceinline__ float dec_f32(unsigned int e) {
    return __uint_as_float((e & 0x80000000u) ? (e & 0x7FFFFFFFu) : ~e);
}

// ---------------------------------------------------------------------------
// proj_kernel (MFMA): Wh = x @ W per head, fp16 MFMA 16x16x32.
//   A-frags: direct global loads of x rows (fp32 converts on the fly).
//   B: W^T staged to LDS fp16. Emits WhT[bh][d][n] fp16 (LDS transpose),
//   s_i/s_j fp32, and M[bh] = max_n s_j via atomicMax (for safe softmax max:
//   max_j leaky(s_i+s_j) = leaky(s_i + M) -- exact for full adjacency).
// PACK: blockIdx.y==24 blocks instead pack adj>0 into bitmask adjb[N][16].
// Block: 32 rows x 64 d. Grid (N/32, B*NH (+1 if PACK)).
// ---------------------------------------------------------------------------
template <int KIN, bool XF32, bool PACK>
__global__ __launch_bounds__(256) void proj_kernel(
    const void* __restrict__ xin_,   // [B][N][KIN] fp32 (XF32) or fp16
    const float* __restrict__ W,     // [NH][KIN][D] fp32
    const float* __restrict__ a,     // [NH][2*D] fp32
    _Float16* __restrict__ WhT,      // [B*NH][D][N] fp16
    float* __restrict__ si,          // [B*NH][N]
    float* __restrict__ sj,          // [B*NH][N]
    unsigned int* __restrict__ Menc, // [B*NH] encoded max sj
    const float* __restrict__ adj,   // [N][N] (PACK only)
    unsigned long long* __restrict__ adjb)  // [N][16] (PACK only)
{
    const int tid = threadIdx.x;
    const int bh  = blockIdx.y;

    if (PACK && bh == NHc * Bc) {
        // ---- adjacency bit-pack: 32 blocks x 32 rows each
        const int px = blockIdx.x, wv = tid >> 6, lane = tid & 63;
        for (int r8 = 0; r8 < 8; ++r8) {
            const int i = px * 32 + wv * 8 + r8;
            unsigned long long word = 0;
            for (int g = 0; g < 16; ++g) {
                bool c = adj[(size_t)i * Nc + g * 64 + lane] > 0.f;
                unsigned long long bal = __ballot(c);
                if (lane == g) word = bal;
            }
            if (lane < 16) adjb[(size_t)i * 16 + lane] = word;
        }
        return;
    }

    __shared__ union {
        _Float16 Bs[64][KIN + 8];
        _Float16 Ts[64][40];
    } u;
    __shared__ float spsA_i[32], spsA_j[32], spsB_i[32], spsB_j[32];

    const int b    = bh / NHc;
    const int hh   = bh % NHc;
    const int row0 = blockIdx.x * 32;

    for (int e = tid; e < KIN * 64; e += 256) {
        int k = e >> 6, d = e & 63;
        u.Bs[d][k] = (_Float16)W[(size_t)hh * KIN * 64 + e];
    }
    __syncthreads();

    const int lane  = tid & 63, wv = tid >> 6;
    const int mblk  = (wv & 1) * 16;
    const int nhalf = (wv >> 1) * 32;
    const int fr    = lane & 15, fq = lane >> 4;

    floatx4 acc0 = {0.f, 0.f, 0.f, 0.f};
    floatx4 acc1 = {0.f, 0.f, 0.f, 0.f};
    const int row = row0 + mblk + fr;

#pragma unroll
    for (int ks = 0; ks < KIN / 32; ++ks) {
        const int k0 = ks * 32 + fq * 8;
        half8 af;
        if (XF32) {
            const float* xr = (const float*)xin_ + ((size_t)b * Nc + row) * KIN + k0;
            float4 u0 = *(const float4*)xr;
            float4 u1 = *(const float4*)(xr + 4);
            af[0] = (_Float16)u0.x; af[1] = (_Float16)u0.y;
            af[2] = (_Float16)u0.z; af[3] = (_Float16)u0.w;
            af[4] = (_Float16)u1.x; af[5] = (_Float16)u1.y;
            af[6] = (_Float16)u1.z; af[7] = (_Float16)u1.w;
        } else {
            af = *(const half8*)((const _Float16*)xin_ + ((size_t)b * Nc + row) * KIN + k0);
        }
        half8 b0 = *(const half8*)&u.Bs[nhalf + fr][k0];
        half8 b1 = *(const half8*)&u.Bs[nhalf + 16 + fr][k0];
        acc0 = __builtin_amdgcn_mfma_f32_16x16x32_f16(af, b0, acc0, 0, 0, 0);
        acc1 = __builtin_amdgcn_mfma_f32_16x16x32_f16(af, b1, acc1, 0, 0, 0);
    }

    // fused s_i / s_j
    const float al0 = a[hh * 2 * Dc + nhalf + fr];
    const float al1 = a[hh * 2 * Dc + nhalf + 16 + fr];
    const float ar0 = a[hh * 2 * Dc + Dc + nhalf + fr];
    const float ar1 = a[hh * 2 * Dc + Dc + nhalf + 16 + fr];
    float pi[4], pj[4];
#pragma unroll
    for (int r = 0; r < 4; ++r) {
        pi[r] = acc0[r] * al0 + acc1[r] * al1;
        pj[r] = acc0[r] * ar0 + acc1[r] * ar1;
        for (int off = 8; off >= 1; off >>= 1) {
            pi[r] += __shfl_xor(pi[r], off, 64);
            pj[r] += __shfl_xor(pj[r], off, 64);
        }
    }
    if (fr == 0) {
#pragma unroll
        for (int r = 0; r < 4; ++r) {
            int lr = mblk + fq * 4 + r;
            if (nhalf == 0) { spsA_i[lr] = pi[r]; spsA_j[lr] = pj[r]; }
            else            { spsB_i[lr] = pi[r]; spsB_j[lr] = pj[r]; }
        }
    }
    __syncthreads();
    if (tid < 64) {   // wave 0: write si/sj, block-max sj -> atomicMax M[bh]
        float vj = -INFINITY;
        if (tid < 32) {
            size_t g = (size_t)bh * Nc + row0 + tid;
            si[g] = spsA_i[tid] + spsB_i[tid];
            vj    = spsA_j[tid] + spsB_j[tid];
            sj[g] = vj;
        }
        float mv = vj;
        for (int off = 32; off >= 1; off >>= 1) mv = fmaxf(mv, __shfl_xor(mv, off, 64));
        if (tid == 0) atomicMax(&Menc[bh], enc_f32(mv));
    }

    // Wh -> fp16 transposed through LDS
#pragma unroll
    for (int nt = 0; nt < 2; ++nt) {
        const int d = nhalf + nt * 16 + fr;
        floatx4 acc = nt ? acc1 : acc0;
#pragma unroll
        for (int p = 0; p < 2; ++p) {
            union { unsigned int w; _Float16 h[2]; } pk;
            pk.h[0] = (_Float16)acc[2 * p];
            pk.h[1] = (_Float16)acc[2 * p + 1];
            *(unsigned int*)&u.Ts[d][mblk + fq * 4 + 2 * p] = pk.w;
        }
    }
    __syncthreads();
    {
        const int d = tid >> 2, ch = tid & 3;
        uint4 v = *(const uint4*)&u.Ts[d][ch * 8];
        *(uint4*)&WhT[(((size_t)bh * Dc + d) << 10) + row0 + ch * 8] = v;
    }
}

// ---------------------------------------------------------------------------
// aggr_kernel: out[row][hh*D+d] = (1/Z_r) * sum_j exp(leaky(s_i+s_j)-m_r)*Wh[j][d]
// ZERO LDS, ZERO BARRIERS. One wave = 16 rows x 64 d x K=1024.
// Lane owns A-row m=lane&15: s_i, m_i = leaky(s_i+M) in registers; computes
// its own A-fragments; Z accumulated online (fp32), shfl-reduced at end.
// Grid: 256 blocks x 384 threads = 1536 waves = 24 bh x 64 row-chunks.
// ---------------------------------------------------------------------------
template <bool DO_ELU, typename OutT>
__global__ __launch_bounds__(384) void aggr_kernel(
    const _Float16* __restrict__ WhT,  // [B*NH][D][N] fp16
    const float* __restrict__ si,
    const float* __restrict__ sj,
    const unsigned int* __restrict__ Menc,
    const unsigned long long* __restrict__ adjb,
    OutT* __restrict__ out)            // [B][N][HID]
{
    const int tid  = threadIdx.x;
    const int gw   = blockIdx.x * 6 + (tid >> 6);
    const int lane = tid & 63;
    const int bh   = gw >> 6;
    const int b    = bh / NHc, hh = bh % NHc;
    const int row0 = (gw & 63) << 4;
    const int fr   = lane & 15, fq = lane >> 4;
    const int row  = row0 + fr;

    const float M   = dec_f32(Menc[bh]);
    const float s_i = si[(size_t)bh * Nc + row];
    const float em  = s_i + M;
    const float m_i = fmaxf(em, ALPHAc * em);  // = max_j leaky(s_i+s_j) (full adj)

    const float* sjr = sj + (size_t)bh * Nc;
    const unsigned long long* arow = adjb + (size_t)row * 16;
    const _Float16* Bp = WhT + (size_t)bh * Dc * Nc;

    floatx4 acc[4] = {{0.f,0.f,0.f,0.f},{0.f,0.f,0.f,0.f},
                      {0.f,0.f,0.f,0.f},{0.f,0.f,0.f,0.f}};
    float zacc = 0.f;

#pragma unroll 4
    for (int s = 0; s < 32; ++s) {
        const int j0 = s * 32 + fq * 8;
        const float4 sa = *(const float4*)&sjr[j0];
        const float4 sb = *(const float4*)&sjr[j0 + 4];
        const unsigned long long w = arow[s >> 1];
        const float sv[8] = {sa.x, sa.y, sa.z, sa.w, sb.x, sb.y, sb.z, sb.w};
        const int bb = (s & 1) * 32 + fq * 8;
        float p[8];
        if (w == ~0ULL) {          // all-connected fast path (uniform on real data)
#pragma unroll
            for (int t = 0; t < 8; ++t) {
                float e = s_i + sv[t];
                e = fmaxf(e, ALPHAc * e) - m_i;
                p[t] = __expf(e);
            }
        } else {
#pragma unroll
            for (int t = 0; t < 8; ++t) {
                float e = s_i + sv[t];
                e = fmaxf(e, ALPHAc * e) - m_i;
                e = ((w >> (bb + t)) & 1) ? e : -1e30f;
                p[t] = __expf(e);
            }
        }
        zacc += ((p[0] + p[1]) + (p[2] + p[3])) + ((p[4] + p[5]) + (p[6] + p[7]));
        union { half8 v; _Float16 h[8]; } A;
#pragma unroll
        for (int t = 0; t < 8; ++t) A.h[t] = (_Float16)p[t];
#pragma unroll
        for (int c = 0; c < 4; ++c) {
            half8 bf = *(const half8*)&Bp[((size_t)(c * 16 + fr) << 10) + j0];
            acc[c] = __builtin_amdgcn_mfma_f32_16x16x32_f16(A.v, bf, acc[c], 0, 0, 0);
        }
    }

    // Z: sum the 4 fq-partials of each row (lanes m, m+16, m+32, m+48)
    zacc += __shfl_xor(zacc, 16, 64);
    zacc += __shfl_xor(zacc, 32, 64);

    // epilogue: C/D layout col=lane&15, row=fq*4+reg
#pragma unroll
    for (int reg = 0; reg < 4; ++reg) {
        const int r  = fq * 4 + reg;
        const float iz = 1.f / __shfl(zacc, r, 64);   // lane r holds Z[row0+r]
#pragma unroll
        for (int c = 0; c < 4; ++c) {
            float v = acc[c][reg] * iz;
            if (DO_ELU) v = v > 0.f ? v : expm1f(v);
            out[((size_t)b * Nc + row0 + r) * HIDc + hh * Dc + c * 16 + fr] = (OutT)v;
        }
    }
}

// ---------------------------------------------------------------------------
extern "C" void kernel_launch(void* const* d_in, const int* in_sizes, int n_in,
                              void* d_out, int out_size, void* d_ws, size_t ws_size,
                              hipStream_t stream) {
    const float* h_in = (const float*)d_in[0];   // (B,N,OBS)
    const float* adj  = (const float*)d_in[1];   // (N,N)
    const float* W1   = (const float*)d_in[2];   // (NH,OBS,D)
    const float* a1   = (const float*)d_in[3];   // (NH,2D)
    const float* W2   = (const float*)d_in[4];   // (NH,HID,D)
    const float* a2   = (const float*)d_in[5];   // (NH,2D)
    float* out = (float*)d_out;

    float* ws = (float*)d_ws;
    const size_t nWhT_f = (size_t)Bc * NHc * Dc * Nc / 2;   // 786432
    const size_t nXh_f  = (size_t)Bc * Nc * HIDc / 2;       // 786432
    const size_t nAb_f  = (size_t)Nc * 16 * 2;              // 32768
    const size_t nR     = (size_t)Bc * NHc * Nc;            // 24576
    _Float16* WhT = (_Float16*)ws;
    _Float16* xh  = (_Float16*)(ws + nWhT_f);
    unsigned long long* adjb = (unsigned long long*)(ws + nWhT_f + nXh_f);
    float* si = ws + nWhT_f + nXh_f + nAb_f;
    float* sj = si + nR;
    unsigned int* Menc = (unsigned int*)(sj + nR);   // 48 slots (24 per layer)

    hipMemsetAsync(Menc, 0, 48 * sizeof(unsigned int), stream);  // enc(-maxfloat) < 0x00800000

    dim3 projGrid1(Nc / 32, Bc * NHc + 1);   // +1 y-slice: adj bit-pack
    dim3 projGrid2(Nc / 32, Bc * NHc);

    // ----- Layer 1 -----
    proj_kernel<OBSc, true, true><<<projGrid1, 256, 0, stream>>>(
        h_in, W1, a1, WhT, si, sj, Menc, adj, adjb);
    aggr_kernel<true, _Float16><<<256, 384, 0, stream>>>(
        WhT, si, sj, Menc, adjb, xh);

    // ----- Layer 2 -----
    proj_kernel<HIDc, false, false><<<projGrid2, 256, 0, stream>>>(
        xh, W2, a2, WhT, si, sj, Menc + 24, nullptr, nullptr);
    aggr_kernel<false, float><<<256, 384, 0, stream>>>(
        WhT, si, sj, Menc + 24, adjb, out);
}

// Round 6
// 143.415 us; speedup vs baseline: 2.6396x; 1.1236x over previous
//
#include <hip/hip_runtime.h>
#include <math.h>

// Problem constants (GNNObservationEncoder: 2-layer GAT, full graph)
#define Bc   8
#define Nc   1024
#define OBSc 64
#define HIDc 192
#define NHc  3
#define Dc   64
#define ALPHAc 0.2f

typedef __attribute__((ext_vector_type(8))) _Float16 half8;
typedef __attribute__((ext_vector_type(4))) float floatx4;

// monotone float->uint encoding for atomicMax-based float max
__device__ __forceinline__ unsigned int enc_f32(float f) {
    unsigned int u = __float_as_uint(f);
    return (u & 0x80000000u) ? ~u : (u | 0x80000000u);
}
__device__ __forceinline__ float dec_f32(unsigned int e) {
    return __uint_as_float((e & 0x80000000u) ? (e & 0x7FFFFFFFu) : ~e);
}

// WhT swizzled (MFMA B-fragment order):
//   idx(bh, jt, c, lane, t) = (((bh*32 + jt)*4 + c)*64 + lane)*8 + t
//   element = Wh[j = jt*32 + (lane>>4)*8 + t][d = c*16 + (lane&15)]
// A wave's B-load for (jt, c) is lane-contiguous 16 B/lane (1 KB, coalesced).

// ---------------------------------------------------------------------------
// proj1_kernel: Wh = x @ W1 (fp16 MFMA), x fp32 direct-global A, W1 staged LDS.
// Emits swizzled WhT, s_i/s_j, M[bh]=max sj (atomicMax).
// Extra y-slice (bh==24): adj bit-pack + W2 -> swizzled fp16 table for proj2.
// ---------------------------------------------------------------------------
__global__ __launch_bounds__(256) void proj1_kernel(
    const float* __restrict__ xin,   // [B][N][OBS]
    const float* __restrict__ W1,    // [NH][OBS][D]
    const float* __restrict__ a,     // [NH][2D]
    _Float16* __restrict__ WhT,
    float* __restrict__ si, float* __restrict__ sj,
    unsigned int* __restrict__ Menc,
    const float* __restrict__ adj,
    unsigned long long* __restrict__ adjb,   // [N][16]
    const float* __restrict__ W2,    // [NH][HID][D]
    _Float16* __restrict__ W2T)      // swizzled 36864 halves
{
    const int tid = threadIdx.x;
    const int bh  = blockIdx.y;

    if (bh == Bc * NHc) {
        const int px = blockIdx.x, wv = tid >> 6, lane = tid & 63;
        for (int r8 = 0; r8 < 8; ++r8) {
            const int i = px * 32 + wv * 8 + r8;
            unsigned long long word = 0;
            for (int g = 0; g < 16; ++g) {
                bool c = adj[(size_t)i * Nc + g * 64 + lane] > 0.f;
                unsigned long long bal = __ballot(c);
                if (lane == g) word = bal;
            }
            if (lane < 16) adjb[(size_t)i * 16 + lane] = word;
        }
        if (px < 12) {
            // W2 -> swizzled fp16: idx = (((hh*6+ks)*2+nh)*2+p)*512 + ln*8 + t
            for (int e = px * 3072 + tid; e < px * 3072 + 3072; e += 256) {
                int t = e & 7, ln = (e >> 3) & 63, p = (e >> 9) & 1, nh = (e >> 10) & 1;
                int g = e >> 11; int ks = g % 6, hh = g / 6;
                int k = ks * 32 + (ln >> 4) * 8 + t;
                int d = nh * 32 + p * 16 + (ln & 15);
                W2T[e] = (_Float16)W2[((size_t)hh * HIDc + k) * Dc + d];
            }
        }
        return;
    }

    __shared__ union {
        _Float16 Bs[64][OBSc + 8];
        _Float16 Ts[64][40];
    } u;
    __shared__ float spsA_i[32], spsA_j[32], spsB_i[32], spsB_j[32];

    const int b = bh / NHc, hh = bh % NHc;
    const int row0 = blockIdx.x * 32;

    for (int e = tid; e < OBSc * 64; e += 256) {
        int k = e >> 6, d = e & 63;
        u.Bs[d][k] = (_Float16)W1[(size_t)hh * OBSc * 64 + e];
    }
    __syncthreads();

    const int lane = tid & 63, wv = tid >> 6;
    const int mblk = (wv & 1) * 16, nhalf = (wv >> 1) * 32;
    const int fr = lane & 15, fq = lane >> 4;
    floatx4 acc0 = {0.f,0.f,0.f,0.f}, acc1 = {0.f,0.f,0.f,0.f};
    const int row = row0 + mblk + fr;

#pragma unroll
    for (int ks = 0; ks < OBSc / 32; ++ks) {
        const int k0 = ks * 32 + fq * 8;
        const float* xr = xin + ((size_t)b * Nc + row) * OBSc + k0;
        float4 u0 = *(const float4*)xr;
        float4 u1 = *(const float4*)(xr + 4);
        half8 af;
        af[0] = (_Float16)u0.x; af[1] = (_Float16)u0.y;
        af[2] = (_Float16)u0.z; af[3] = (_Float16)u0.w;
        af[4] = (_Float16)u1.x; af[5] = (_Float16)u1.y;
        af[6] = (_Float16)u1.z; af[7] = (_Float16)u1.w;
        half8 b0 = *(const half8*)&u.Bs[nhalf + fr][k0];
        half8 b1 = *(const half8*)&u.Bs[nhalf + 16 + fr][k0];
        acc0 = __builtin_amdgcn_mfma_f32_16x16x32_f16(af, b0, acc0, 0, 0, 0);
        acc1 = __builtin_amdgcn_mfma_f32_16x16x32_f16(af, b1, acc1, 0, 0, 0);
    }

    // fused s_i / s_j
    const float al0 = a[hh * 2 * Dc + nhalf + fr];
    const float al1 = a[hh * 2 * Dc + nhalf + 16 + fr];
    const float ar0 = a[hh * 2 * Dc + Dc + nhalf + fr];
    const float ar1 = a[hh * 2 * Dc + Dc + nhalf + 16 + fr];
    float pi[4], pj[4];
#pragma unroll
    for (int r = 0; r < 4; ++r) {
        pi[r] = acc0[r] * al0 + acc1[r] * al1;
        pj[r] = acc0[r] * ar0 + acc1[r] * ar1;
        for (int off = 8; off >= 1; off >>= 1) {
            pi[r] += __shfl_xor(pi[r], off, 64);
            pj[r] += __shfl_xor(pj[r], off, 64);
        }
    }
    if (fr == 0) {
#pragma unroll
        for (int r = 0; r < 4; ++r) {
            int lr = mblk + fq * 4 + r;
            if (nhalf == 0) { spsA_i[lr] = pi[r]; spsA_j[lr] = pj[r]; }
            else            { spsB_i[lr] = pi[r]; spsB_j[lr] = pj[r]; }
        }
    }
    __syncthreads();   // sps ready; Bs reads done (Ts may now overwrite)
    if (tid < 64) {
        float vj = -INFINITY;
        if (tid < 32) {
            size_t g = (size_t)bh * Nc + row0 + tid;
            si[g] = spsA_i[tid] + spsB_i[tid];
            vj    = spsA_j[tid] + spsB_j[tid];
            sj[g] = vj;
        }
        float mv = vj;
        for (int off = 32; off >= 1; off >>= 1) mv = fmaxf(mv, __shfl_xor(mv, off, 64));
        if (tid == 0) atomicMax(&Menc[bh], enc_f32(mv));
    }

    // Wh -> Ts[d][local n]
#pragma unroll
    for (int nt = 0; nt < 2; ++nt) {
        const int d = nhalf + nt * 16 + fr;
        floatx4 acc = nt ? acc1 : acc0;
#pragma unroll
        for (int p = 0; p < 2; ++p) {
            union { unsigned int w; _Float16 h[2]; } pk;
            pk.h[0] = (_Float16)acc[2 * p];
            pk.h[1] = (_Float16)acc[2 * p + 1];
            *(unsigned int*)&u.Ts[d][mblk + fq * 4 + 2 * p] = pk.w;
        }
    }
    __syncthreads();
    {   // swizzled store: thread tid covers (c=tid>>6, lane2=tid&63)
        const int c2 = tid >> 6, lane2 = tid & 63;
        const int fr2 = lane2 & 15, fq2 = lane2 >> 4;
        const int jt = row0 >> 5;
        uint4 v = *(const uint4*)&u.Ts[c2 * 16 + fr2][fq2 * 8];
        *(uint4*)&WhT[(size_t)(bh * 32 + jt) * 2048 + tid * 8] = v;
    }
}

// ---------------------------------------------------------------------------
// proj2_kernel: Wh = x @ W2 (fp16 MFMA), A from global fp16 xh, B from the
// L2-hot swizzled W2T table (no LDS staging, no staging barrier).
// ---------------------------------------------------------------------------
__global__ __launch_bounds__(256) void proj2_kernel(
    const _Float16* __restrict__ xh,   // [B][N][HID] fp16
    const _Float16* __restrict__ W2T,
    const float* __restrict__ a,
    _Float16* __restrict__ WhT,
    float* __restrict__ si, float* __restrict__ sj,
    unsigned int* __restrict__ Menc)
{
    __shared__ _Float16 Ts[64][40];
    __shared__ float spsA_i[32], spsA_j[32], spsB_i[32], spsB_j[32];

    const int tid = threadIdx.x, bh = blockIdx.y;
    const int b = bh / NHc, hh = bh % NHc;
    const int row0 = blockIdx.x * 32;
    const int lane = tid & 63, wv = tid >> 6;
    const int mblk = (wv & 1) * 16, nhalf = (wv >> 1) * 32;
    const int fr = lane & 15, fq = lane >> 4;
    const int nh = nhalf >> 5;

    floatx4 acc0 = {0.f,0.f,0.f,0.f}, acc1 = {0.f,0.f,0.f,0.f};
    const int row = row0 + mblk + fr;

#pragma unroll
    for (int ks = 0; ks < HIDc / 32; ++ks) {
        half8 af = *(const half8*)&xh[((size_t)b * Nc + row) * HIDc + ks * 32 + fq * 8];
        const _Float16* wb = W2T + (size_t)((hh * 6 + ks) * 2 + nh) * 1024 + lane * 8;
        half8 b0 = *(const half8*)wb;
        half8 b1 = *(const half8*)(wb + 512);
        acc0 = __builtin_amdgcn_mfma_f32_16x16x32_f16(af, b0, acc0, 0, 0, 0);
        acc1 = __builtin_amdgcn_mfma_f32_16x16x32_f16(af, b1, acc1, 0, 0, 0);
    }

    const float al0 = a[hh * 2 * Dc + nhalf + fr];
    const float al1 = a[hh * 2 * Dc + nhalf + 16 + fr];
    const float ar0 = a[hh * 2 * Dc + Dc + nhalf + fr];
    const float ar1 = a[hh * 2 * Dc + Dc + nhalf + 16 + fr];
    float pi[4], pj[4];
#pragma unroll
    for (int r = 0; r < 4; ++r) {
        pi[r] = acc0[r] * al0 + acc1[r] * al1;
        pj[r] = acc0[r] * ar0 + acc1[r] * ar1;
        for (int off = 8; off >= 1; off >>= 1) {
            pi[r] += __shfl_xor(pi[r], off, 64);
            pj[r] += __shfl_xor(pj[r], off, 64);
        }
    }
    if (fr == 0) {
#pragma unroll
        for (int r = 0; r < 4; ++r) {
            int lr = mblk + fq * 4 + r;
            if (nhalf == 0) { spsA_i[lr] = pi[r]; spsA_j[lr] = pj[r]; }
            else            { spsB_i[lr] = pi[r]; spsB_j[lr] = pj[r]; }
        }
    }
    __syncthreads();
    if (tid < 64) {
        float vj = -INFINITY;
        if (tid < 32) {
            size_t g = (size_t)bh * Nc + row0 + tid;
            si[g] = spsA_i[tid] + spsB_i[tid];
            vj    = spsA_j[tid] + spsB_j[tid];
            sj[g] = vj;
        }
        float mv = vj;
        for (int off = 32; off >= 1; off >>= 1) mv = fmaxf(mv, __shfl_xor(mv, off, 64));
        if (tid == 0) atomicMax(&Menc[bh], enc_f32(mv));
    }

#pragma unroll
    for (int nt = 0; nt < 2; ++nt) {
        const int d = nhalf + nt * 16 + fr;
        floatx4 acc = nt ? acc1 : acc0;
#pragma unroll
        for (int p = 0; p < 2; ++p) {
            union { unsigned int w; _Float16 h[2]; } pk;
            pk.h[0] = (_Float16)acc[2 * p];
            pk.h[1] = (_Float16)acc[2 * p + 1];
            *(unsigned int*)&Ts[d][mblk + fq * 4 + 2 * p] = pk.w;
        }
    }
    __syncthreads();
    {
        const int c2 = tid >> 6, lane2 = tid & 63;
        const int fr2 = lane2 & 15, fq2 = lane2 >> 4;
        const int jt = row0 >> 5;
        uint4 v = *(const uint4*)&Ts[c2 * 16 + fr2][fq2 * 8];
        *(uint4*)&WhT[(size_t)(bh * 32 + jt) * 2048 + tid * 8] = v;
    }
}

// ---------------------------------------------------------------------------
// aggr_kernel: out[row][hh*D+d] = (1/Z_r) * sum_j exp(leaky(s_i+s_j)-m_r)*Wh[j][d]
// Block = 4 waves, each wave a K=256 slice of the same (bh, 16-row chunk);
// barrier-free K-loop; ONE end-of-kernel LDS reduction for acc + Z.
// Grid: 1536 blocks x 256 thr = 6144 waves = 24 waves/CU.
// ---------------------------------------------------------------------------
template <bool DO_ELU, typename OutT>
__global__ __launch_bounds__(256, 6) void aggr_kernel(
    const _Float16* __restrict__ WhT,  // swizzled fragment order
    const float* __restrict__ si,
    const float* __restrict__ sj,
    const unsigned int* __restrict__ Menc,
    const unsigned long long* __restrict__ adjb,
    OutT* __restrict__ out)
{
    __shared__ float red[4][64][20];   // [wave][lane][c*4+reg], pad 20: 2-way max
    __shared__ float zs[4][16];

    const int tid  = threadIdx.x;
    const int wv   = tid >> 6, lane = tid & 63;
    const int bh   = blockIdx.x >> 6;
    const int row0 = (blockIdx.x & 63) << 4;
    const int b    = bh / NHc, hh = bh % NHc;
    const int fr   = lane & 15, fq = lane >> 4;
    const int row  = row0 + fr;

    const float M   = dec_f32(Menc[bh]);
    const float s_i = si[(size_t)bh * Nc + row];
    const float em  = s_i + M;
    const float m_i = fmaxf(em, ALPHAc * em);  // = max_j leaky(s_i+s_j), full adj

    const float* sjr = sj + (size_t)bh * Nc;
    const unsigned long long* arow = adjb + (size_t)row * 16;
    const _Float16* Bp = WhT + (size_t)bh * 32 * 2048;

    floatx4 acc[4] = {{0.f,0.f,0.f,0.f},{0.f,0.f,0.f,0.f},
                      {0.f,0.f,0.f,0.f},{0.f,0.f,0.f,0.f}};
    float zacc = 0.f;

#pragma unroll 2
    for (int s8 = 0; s8 < 8; ++s8) {
        const int s  = wv * 8 + s8;
        const int j0 = s * 32 + fq * 8;
        const float4 sa = *(const float4*)&sjr[j0];
        const float4 sb = *(const float4*)&sjr[j0 + 4];
        const unsigned long long w = arow[s >> 1];
        const int bb = (s & 1) * 32 + fq * 8;
        const float sv[8] = {sa.x, sa.y, sa.z, sa.w, sb.x, sb.y, sb.z, sb.w};
        float p[8];
        if (w == ~0ULL) {    // all-connected fast path
#pragma unroll
            for (int t = 0; t < 8; ++t) {
                float e = s_i + sv[t];
                e = fmaxf(e, ALPHAc * e) - m_i;
                p[t] = __expf(e);
            }
        } else {
#pragma unroll
            for (int t = 0; t < 8; ++t) {
                float e = s_i + sv[t];
                e = fmaxf(e, ALPHAc * e) - m_i;
                e = ((w >> (bb + t)) & 1) ? e : -1e30f;
                p[t] = __expf(e);
            }
        }
        zacc += ((p[0] + p[1]) + (p[2] + p[3])) + ((p[4] + p[5]) + (p[6] + p[7]));
        union { half8 v; _Float16 h[8]; } A;
#pragma unroll
        for (int t = 0; t < 8; ++t) A.h[t] = (_Float16)p[t];
        const _Float16* bbase = Bp + (size_t)s * 4 * 512 + lane * 8;
#pragma unroll
        for (int c = 0; c < 4; ++c) {
            half8 bf = *(const half8*)(bbase + c * 512);   // 16 B/lane coalesced
            acc[c] = __builtin_amdgcn_mfma_f32_16x16x32_f16(A.v, bf, acc[c], 0, 0, 0);
        }
    }

    // per-wave Z: sum fq-partials -> every lane holds Z_wv[row0 + (lane&15)]
    zacc += __shfl_xor(zacc, 16, 64);
    zacc += __shfl_xor(zacc, 32, 64);
    if (lane < 16) zs[wv][lane] = zacc;
#pragma unroll
    for (int c = 0; c < 4; ++c)
        *(floatx4*)&red[wv][lane][c * 4] = acc[c];
    __syncthreads();

    // wave wv finalizes column block c = wv
    floatx4 af = {0.f, 0.f, 0.f, 0.f};
#pragma unroll
    for (int w = 0; w < 4; ++w) {
        floatx4 r = *(const floatx4*)&red[w][lane][wv * 4];
        af[0] += r[0]; af[1] += r[1]; af[2] += r[2]; af[3] += r[3];
    }
#pragma unroll
    for (int reg = 0; reg < 4; ++reg) {
        const int r = fq * 4 + reg;
        const float Z = (zs[0][r] + zs[1][r]) + (zs[2][r] + zs[3][r]);
        float v = af[reg] / Z;
        if (DO_ELU) v = v > 0.f ? v : expm1f(v);
        out[((size_t)b * Nc + row0 + r) * HIDc + hh * Dc + wv * 16 + fr] = (OutT)v;
    }
}

// ---------------------------------------------------------------------------
extern "C" void kernel_launch(void* const* d_in, const int* in_sizes, int n_in,
                              void* d_out, int out_size, void* d_ws, size_t ws_size,
                              hipStream_t stream) {
    const float* h_in = (const float*)d_in[0];   // (B,N,OBS)
    const float* adj  = (const float*)d_in[1];   // (N,N)
    const float* W1   = (const float*)d_in[2];   // (NH,OBS,D)
    const float* a1   = (const float*)d_in[3];   // (NH,2D)
    const float* W2   = (const float*)d_in[4];   // (NH,HID,D)
    const float* a2   = (const float*)d_in[5];   // (NH,2D)
    float* out = (float*)d_out;

    float* ws = (float*)d_ws;
    const size_t nWhT_f = (size_t)Bc * NHc * Dc * Nc / 2;   // 786432
    const size_t nXh_f  = (size_t)Bc * Nc * HIDc / 2;       // 786432
    const size_t nAb_f  = (size_t)Nc * 16 * 2;              // 32768
    const size_t nW2T_f = 36864 / 2;                        // 18432
    const size_t nR     = (size_t)Bc * NHc * Nc;            // 24576
    _Float16* WhT = (_Float16*)ws;
    _Float16* xh  = (_Float16*)(ws + nWhT_f);
    unsigned long long* adjb = (unsigned long long*)(ws + nWhT_f + nXh_f);
    _Float16* W2T = (_Float16*)(ws + nWhT_f + nXh_f + nAb_f);
    float* si = ws + nWhT_f + nXh_f + nAb_f + nW2T_f;
    float* sj = si + nR;
    unsigned int* Menc = (unsigned int*)(sj + nR);   // 48 slots

    (void)hipMemsetAsync(Menc, 0, 48 * sizeof(unsigned int), stream);

    dim3 projGrid1(Nc / 32, Bc * NHc + 1);   // +1 y-slice: adj pack + W2 convert
    dim3 projGrid2(Nc / 32, Bc * NHc);

    // ----- Layer 1 -----
    proj1_kernel<<<projGrid1, 256, 0, stream>>>(
        h_in, W1, a1, WhT, si, sj, Menc, adj, adjb, W2, W2T);
    aggr_kernel<true, _Float16><<<1536, 256, 0, stream>>>(
        WhT, si, sj, Menc, adjb, xh);

    // ----- Layer 2 -----
    proj2_kernel<<<projGrid2, 256, 0, stream>>>(
        xh, W2T, a2, WhT, si, sj, Menc + 24);
    aggr_kernel<false, float><<<1536, 256, 0, stream>>>(
        WhT, si, sj, Menc + 24, adjb, out);
}

// Round 7
// 135.998 us; speedup vs baseline: 2.7835x; 1.0545x over previous
//
#include <hip/hip_runtime.h>
#include <math.h>

// Problem constants (GNNObservationEncoder: 2-layer GAT, full graph)
#define Bc   8
#define Nc   1024
#define OBSc 64
#define HIDc 192
#define NHc  3
#define Dc   64
#define ALPHAc 0.2f

typedef __attribute__((ext_vector_type(8))) _Float16 half8;
typedef __attribute__((ext_vector_type(4))) float floatx4;

// monotone float->uint encoding for atomicMax-based float max
__device__ __forceinline__ unsigned int enc_f32(float f) {
    unsigned int u = __float_as_uint(f);
    return (u & 0x80000000u) ? ~u : (u | 0x80000000u);
}
__device__ __forceinline__ float dec_f32(unsigned int e) {
    return __uint_as_float((e & 0x80000000u) ? (e & 0x7FFFFFFFu) : ~e);
}

// WhT swizzled (MFMA B-fragment order):
//   idx(bh, jt, c, lane, t) = (((bh*32 + jt)*4 + c)*64 + lane)*8 + t
//   element = Wh[j = jt*32 + (lane>>4)*8 + t][d = c*16 + (lane&15)]

// ---------------------------------------------------------------------------
// proj1_kernel: Wh = x @ W1 (fp16 MFMA), x fp32 direct-global A, W1 staged LDS.
// Emits swizzled WhT, s_i/s_j, M[bh]=max sj (atomicMax).
// Extra y-slice (bh==24): adj bit-pack + W2 -> swizzled fp16 table for proj2.
// ---------------------------------------------------------------------------
__global__ __launch_bounds__(256) void proj1_kernel(
    const float* __restrict__ xin,   // [B][N][OBS]
    const float* __restrict__ W1,    // [NH][OBS][D]
    const float* __restrict__ a,     // [NH][2D]
    _Float16* __restrict__ WhT,
    float* __restrict__ si, float* __restrict__ sj,
    unsigned int* __restrict__ Menc,
    const float* __restrict__ adj,
    unsigned long long* __restrict__ adjb,   // [N][16]
    const float* __restrict__ W2,    // [NH][HID][D]
    _Float16* __restrict__ W2T)      // swizzled 36864 halves
{
    const int tid = threadIdx.x;
    const int bh  = blockIdx.y;

    if (bh == Bc * NHc) {
        const int px = blockIdx.x, wv = tid >> 6, lane = tid & 63;
        for (int r8 = 0; r8 < 8; ++r8) {
            const int i = px * 32 + wv * 8 + r8;
            unsigned long long word = 0;
            for (int g = 0; g < 16; ++g) {
                bool c = adj[(size_t)i * Nc + g * 64 + lane] > 0.f;
                unsigned long long bal = __ballot(c);
                if (lane == g) word = bal;
            }
            if (lane < 16) adjb[(size_t)i * 16 + lane] = word;
        }
        if (px < 12) {
            // W2 -> swizzled fp16: idx = (((hh*6+ks)*2+nh)*2+p)*512 + ln*8 + t
            for (int e = px * 3072 + tid; e < px * 3072 + 3072; e += 256) {
                int t = e & 7, ln = (e >> 3) & 63, p = (e >> 9) & 1, nh = (e >> 10) & 1;
                int g = e >> 11; int ks = g % 6, hh = g / 6;
                int k = ks * 32 + (ln >> 4) * 8 + t;
                int d = nh * 32 + p * 16 + (ln & 15);
                W2T[e] = (_Float16)W2[((size_t)hh * HIDc + k) * Dc + d];
            }
        }
        return;
    }

    __shared__ union {
        _Float16 Bs[64][OBSc + 8];
        _Float16 Ts[64][40];
    } u;
    __shared__ float spsA_i[32], spsA_j[32], spsB_i[32], spsB_j[32];

    const int b = bh / NHc, hh = bh % NHc;
    const int row0 = blockIdx.x * 32;

    for (int e = tid; e < OBSc * 64; e += 256) {
        int k = e >> 6, d = e & 63;
        u.Bs[d][k] = (_Float16)W1[(size_t)hh * OBSc * 64 + e];
    }
    __syncthreads();

    const int lane = tid & 63, wv = tid >> 6;
    const int mblk = (wv & 1) * 16, nhalf = (wv >> 1) * 32;
    const int fr = lane & 15, fq = lane >> 4;
    floatx4 acc0 = {0.f,0.f,0.f,0.f}, acc1 = {0.f,0.f,0.f,0.f};
    const int row = row0 + mblk + fr;

#pragma unroll
    for (int ks = 0; ks < OBSc / 32; ++ks) {
        const int k0 = ks * 32 + fq * 8;
        const float* xr = xin + ((size_t)b * Nc + row) * OBSc + k0;
        float4 u0 = *(const float4*)xr;
        float4 u1 = *(const float4*)(xr + 4);
        half8 af;
        af[0] = (_Float16)u0.x; af[1] = (_Float16)u0.y;
        af[2] = (_Float16)u0.z; af[3] = (_Float16)u0.w;
        af[4] = (_Float16)u1.x; af[5] = (_Float16)u1.y;
        af[6] = (_Float16)u1.z; af[7] = (_Float16)u1.w;
        half8 b0 = *(const half8*)&u.Bs[nhalf + fr][k0];
        half8 b1 = *(const half8*)&u.Bs[nhalf + 16 + fr][k0];
        acc0 = __builtin_amdgcn_mfma_f32_16x16x32_f16(af, b0, acc0, 0, 0, 0);
        acc1 = __builtin_amdgcn_mfma_f32_16x16x32_f16(af, b1, acc1, 0, 0, 0);
    }

    // fused s_i / s_j
    const float al0 = a[hh * 2 * Dc + nhalf + fr];
    const float al1 = a[hh * 2 * Dc + nhalf + 16 + fr];
    const float ar0 = a[hh * 2 * Dc + Dc + nhalf + fr];
    const float ar1 = a[hh * 2 * Dc + Dc + nhalf + 16 + fr];
    float pi[4], pj[4];
#pragma unroll
    for (int r = 0; r < 4; ++r) {
        pi[r] = acc0[r] * al0 + acc1[r] * al1;
        pj[r] = acc0[r] * ar0 + acc1[r] * ar1;
        for (int off = 8; off >= 1; off >>= 1) {
            pi[r] += __shfl_xor(pi[r], off, 64);
            pj[r] += __shfl_xor(pj[r], off, 64);
        }
    }
    if (fr == 0) {
#pragma unroll
        for (int r = 0; r < 4; ++r) {
            int lr = mblk + fq * 4 + r;
            if (nhalf == 0) { spsA_i[lr] = pi[r]; spsA_j[lr] = pj[r]; }
            else            { spsB_i[lr] = pi[r]; spsB_j[lr] = pj[r]; }
        }
    }
    __syncthreads();   // sps ready; Bs reads done (Ts may now overwrite)
    if (tid < 64) {
        float vj = -INFINITY;
        if (tid < 32) {
            size_t g = (size_t)bh * Nc + row0 + tid;
            si[g] = spsA_i[tid] + spsB_i[tid];
            vj    = spsA_j[tid] + spsB_j[tid];
            sj[g] = vj;
        }
        float mv = vj;
        for (int off = 32; off >= 1; off >>= 1) mv = fmaxf(mv, __shfl_xor(mv, off, 64));
        if (tid == 0) atomicMax(&Menc[bh], enc_f32(mv));
    }

    // Wh -> Ts[d][local n]
#pragma unroll
    for (int nt = 0; nt < 2; ++nt) {
        const int d = nhalf + nt * 16 + fr;
        floatx4 acc = nt ? acc1 : acc0;
#pragma unroll
        for (int p = 0; p < 2; ++p) {
            union { unsigned int w; _Float16 h[2]; } pk;
            pk.h[0] = (_Float16)acc[2 * p];
            pk.h[1] = (_Float16)acc[2 * p + 1];
            *(unsigned int*)&u.Ts[d][mblk + fq * 4 + 2 * p] = pk.w;
        }
    }
    __syncthreads();
    {   // swizzled store: thread tid covers (c=tid>>6, lane2=tid&63)
        const int c2 = tid >> 6, lane2 = tid & 63;
        const int fr2 = lane2 & 15, fq2 = lane2 >> 4;
        const int jt = row0 >> 5;
        uint4 v = *(const uint4*)&u.Ts[c2 * 16 + fr2][fq2 * 8];
        *(uint4*)&WhT[(size_t)(bh * 32 + jt) * 2048 + tid * 8] = v;
    }
}

// ---------------------------------------------------------------------------
// proj2_kernel: Wh = x @ W2 (fp16 MFMA), A from global fp16 xh, B from the
// L2-hot swizzled W2T table (no LDS staging, no staging barrier).
// ---------------------------------------------------------------------------
__global__ __launch_bounds__(256) void proj2_kernel(
    const _Float16* __restrict__ xh,   // [B][N][HID] fp16
    const _Float16* __restrict__ W2T,
    const float* __restrict__ a,
    _Float16* __restrict__ WhT,
    float* __restrict__ si, float* __restrict__ sj,
    unsigned int* __restrict__ Menc)
{
    __shared__ _Float16 Ts[64][40];
    __shared__ float spsA_i[32], spsA_j[32], spsB_i[32], spsB_j[32];

    const int tid = threadIdx.x, bh = blockIdx.y;
    const int b = bh / NHc, hh = bh % NHc;
    const int row0 = blockIdx.x * 32;
    const int lane = tid & 63, wv = tid >> 6;
    const int mblk = (wv & 1) * 16, nhalf = (wv >> 1) * 32;
    const int fr = lane & 15, fq = lane >> 4;
    const int nh = nhalf >> 5;

    floatx4 acc0 = {0.f,0.f,0.f,0.f}, acc1 = {0.f,0.f,0.f,0.f};
    const int row = row0 + mblk + fr;

#pragma unroll
    for (int ks = 0; ks < HIDc / 32; ++ks) {
        half8 af = *(const half8*)&xh[((size_t)b * Nc + row) * HIDc + ks * 32 + fq * 8];
        const _Float16* wb = W2T + (size_t)((hh * 6 + ks) * 2 + nh) * 1024 + lane * 8;
        half8 b0 = *(const half8*)wb;
        half8 b1 = *(const half8*)(wb + 512);
        acc0 = __builtin_amdgcn_mfma_f32_16x16x32_f16(af, b0, acc0, 0, 0, 0);
        acc1 = __builtin_amdgcn_mfma_f32_16x16x32_f16(af, b1, acc1, 0, 0, 0);
    }

    const float al0 = a[hh * 2 * Dc + nhalf + fr];
    const float al1 = a[hh * 2 * Dc + nhalf + 16 + fr];
    const float ar0 = a[hh * 2 * Dc + Dc + nhalf + fr];
    const float ar1 = a[hh * 2 * Dc + Dc + nhalf + 16 + fr];
    float pi[4], pj[4];
#pragma unroll
    for (int r = 0; r < 4; ++r) {
        pi[r] = acc0[r] * al0 + acc1[r] * al1;
        pj[r] = acc0[r] * ar0 + acc1[r] * ar1;
        for (int off = 8; off >= 1; off >>= 1) {
            pi[r] += __shfl_xor(pi[r], off, 64);
            pj[r] += __shfl_xor(pj[r], off, 64);
        }
    }
    if (fr == 0) {
#pragma unroll
        for (int r = 0; r < 4; ++r) {
            int lr = mblk + fq * 4 + r;
            if (nhalf == 0) { spsA_i[lr] = pi[r]; spsA_j[lr] = pj[r]; }
            else            { spsB_i[lr] = pi[r]; spsB_j[lr] = pj[r]; }
        }
    }
    __syncthreads();
    if (tid < 64) {
        float vj = -INFINITY;
        if (tid < 32) {
            size_t g = (size_t)bh * Nc + row0 + tid;
            si[g] = spsA_i[tid] + spsB_i[tid];
            vj    = spsA_j[tid] + spsB_j[tid];
            sj[g] = vj;
        }
        float mv = vj;
        for (int off = 32; off >= 1; off >>= 1) mv = fmaxf(mv, __shfl_xor(mv, off, 64));
        if (tid == 0) atomicMax(&Menc[bh], enc_f32(mv));
    }

#pragma unroll
    for (int nt = 0; nt < 2; ++nt) {
        const int d = nhalf + nt * 16 + fr;
        floatx4 acc = nt ? acc1 : acc0;
#pragma unroll
        for (int p = 0; p < 2; ++p) {
            union { unsigned int w; _Float16 h[2]; } pk;
            pk.h[0] = (_Float16)acc[2 * p];
            pk.h[1] = (_Float16)acc[2 * p + 1];
            *(unsigned int*)&Ts[d][mblk + fq * 4 + 2 * p] = pk.w;
        }
    }
    __syncthreads();
    {
        const int c2 = tid >> 6, lane2 = tid & 63;
        const int fr2 = lane2 & 15, fq2 = lane2 >> 4;
        const int jt = row0 >> 5;
        uint4 v = *(const uint4*)&Ts[c2 * 16 + fr2][fq2 * 8];
        *(uint4*)&WhT[(size_t)(bh * 32 + jt) * 2048 + tid * 8] = v;
    }
}

// ---------------------------------------------------------------------------
// aggr_kernel: out[row][hh*D+d] = (1/Z_r) * sum_j exp(leaky(s_i+s_j)-m_r)*Wh[j][d]
// Block = 4 waves, each wave a K=256 slice of the same (bh, 16-row chunk).
// Explicit 2-deep software pipeline: iteration i+1's {sj, adjb, 4 B-frags}
// are issued before iteration i's exp/pack/MFMA chain, so VMEM latency
// overlaps compute. launch_bounds(256,4): VGPR cap 128 gives the allocator
// room for the double register set (R6's (256,6) capped at 40 VGPR ->
// fully serialized loads; that was the bottleneck).
// Grid: 1536 blocks x 256 thr; 4 blocks/CU = 16 waves/CU.
// ---------------------------------------------------------------------------
template <bool DO_ELU, typename OutT>
__global__ __launch_bounds__(256, 4) void aggr_kernel(
    const _Float16* __restrict__ WhT,  // swizzled fragment order
    const float* __restrict__ si,
    const float* __restrict__ sj,
    const unsigned int* __restrict__ Menc,
    const unsigned long long* __restrict__ adjb,
    OutT* __restrict__ out)
{
    __shared__ float red[4][64][20];   // [wave][lane][c*4+reg], pad 20
    __shared__ float zs[4][16];

    const int tid  = threadIdx.x;
    const int wv   = tid >> 6, lane = tid & 63;
    const int bh   = blockIdx.x >> 6;
    const int row0 = (blockIdx.x & 63) << 4;
    const int b    = bh / NHc, hh = bh % NHc;
    const int fr   = lane & 15, fq = lane >> 4;
    const int row  = row0 + fr;

    const float M   = dec_f32(Menc[bh]);
    const float s_i = si[(size_t)bh * Nc + row];
    const float em  = s_i + M;
    const float m_i = fmaxf(em, ALPHAc * em);  // = max_j leaky(s_i+s_j), full adj

    const float* sjr = sj + (size_t)bh * Nc + fq * 8;   // lane-offset base
    const unsigned long long* arow = adjb + (size_t)row * 16;
    // this wave's B-fragment base: s = wv*8 + s8, frag at s*2048 + c*512 + lane*8
    const _Float16* Bp = WhT + (size_t)bh * 65536 + (size_t)wv * 8 * 2048 + lane * 8;

    floatx4 acc[4] = {{0.f,0.f,0.f,0.f},{0.f,0.f,0.f,0.f},
                      {0.f,0.f,0.f,0.f},{0.f,0.f,0.f,0.f}};
    float zacc = 0.f;

    // ---- pipeline prologue: iteration 0 loads
    float4 sa = *(const float4*)&sjr[wv * 256];
    float4 sb = *(const float4*)&sjr[wv * 256 + 4];
    unsigned long long w = arow[(wv * 8) >> 1];
    half8 bfr0 = *(const half8*)(Bp);
    half8 bfr1 = *(const half8*)(Bp + 512);
    half8 bfr2 = *(const half8*)(Bp + 1024);
    half8 bfr3 = *(const half8*)(Bp + 1536);

#pragma unroll
    for (int s8 = 0; s8 < 8; ++s8) {
        const int s = wv * 8 + s8;
        // ---- issue next iteration's loads first (overlap with compute)
        float4 nsa, nsb; unsigned long long nw;
        half8 nb0, nb1, nb2, nb3;
        if (s8 < 7) {
            const int jn = (s + 1) * 32 - wv * 256;   // relative to sjr base? no:
            nsa = *(const float4*)&sjr[(s + 1) * 32];
            nsb = *(const float4*)&sjr[(s + 1) * 32 + 4];
            nw  = arow[(s + 1) >> 1];
            const _Float16* bn = Bp + (size_t)(s8 + 1) * 2048;
            nb0 = *(const half8*)(bn);
            nb1 = *(const half8*)(bn + 512);
            nb2 = *(const half8*)(bn + 1024);
            nb3 = *(const half8*)(bn + 1536);
            (void)jn;
        }
        // ---- exp chain on current regs
        const int bb = (s & 1) * 32 + fq * 8;
        const float sv[8] = {sa.x, sa.y, sa.z, sa.w, sb.x, sb.y, sb.z, sb.w};
        float p[8];
        if (w == ~0ULL) {    // all-connected fast path
#pragma unroll
            for (int t = 0; t < 8; ++t) {
                float e = s_i + sv[t];
                e = fmaxf(e, ALPHAc * e) - m_i;
                p[t] = __expf(e);
            }
        } else {
#pragma unroll
            for (int t = 0; t < 8; ++t) {
                float e = s_i + sv[t];
                e = fmaxf(e, ALPHAc * e) - m_i;
                e = ((w >> (bb + t)) & 1) ? e : -1e30f;
                p[t] = __expf(e);
            }
        }
        zacc += ((p[0] + p[1]) + (p[2] + p[3])) + ((p[4] + p[5]) + (p[6] + p[7]));
        union { half8 v; _Float16 h[8]; } A;
#pragma unroll
        for (int t = 0; t < 8; ++t) A.h[t] = (_Float16)p[t];
        acc[0] = __builtin_amdgcn_mfma_f32_16x16x32_f16(A.v, bfr0, acc[0], 0, 0, 0);
        acc[1] = __builtin_amdgcn_mfma_f32_16x16x32_f16(A.v, bfr1, acc[1], 0, 0, 0);
        acc[2] = __builtin_amdgcn_mfma_f32_16x16x32_f16(A.v, bfr2, acc[2], 0, 0, 0);
        acc[3] = __builtin_amdgcn_mfma_f32_16x16x32_f16(A.v, bfr3, acc[3], 0, 0, 0);
        // ---- rotate pipeline regs
        if (s8 < 7) {
            sa = nsa; sb = nsb; w = nw;
            bfr0 = nb0; bfr1 = nb1; bfr2 = nb2; bfr3 = nb3;
        }
    }

    // per-wave Z: sum fq-partials -> every lane holds Z_wv[row0 + (lane&15)]
    zacc += __shfl_xor(zacc, 16, 64);
    zacc += __shfl_xor(zacc, 32, 64);
    if (lane < 16) zs[wv][lane] = zacc;
#pragma unroll
    for (int c = 0; c < 4; ++c)
        *(floatx4*)&red[wv][lane][c * 4] = acc[c];
    __syncthreads();

    // wave wv finalizes column block c = wv
    floatx4 af = {0.f, 0.f, 0.f, 0.f};
#pragma unroll
    for (int w2 = 0; w2 < 4; ++w2) {
        floatx4 r = *(const floatx4*)&red[w2][lane][wv * 4];
        af[0] += r[0]; af[1] += r[1]; af[2] += r[2]; af[3] += r[3];
    }
#pragma unroll
    for (int reg = 0; reg < 4; ++reg) {
        const int r = fq * 4 + reg;
        const float Z = (zs[0][r] + zs[1][r]) + (zs[2][r] + zs[3][r]);
        float v = af[reg] / Z;
        if (DO_ELU) v = v > 0.f ? v : expm1f(v);
        out[((size_t)b * Nc + row0 + r) * HIDc + hh * Dc + wv * 16 + fr] = (OutT)v;
    }
}

// ---------------------------------------------------------------------------
extern "C" void kernel_launch(void* const* d_in, const int* in_sizes, int n_in,
                              void* d_out, int out_size, void* d_ws, size_t ws_size,
                              hipStream_t stream) {
    const float* h_in = (const float*)d_in[0];   // (B,N,OBS)
    const float* adj  = (const float*)d_in[1];   // (N,N)
    const float* W1   = (const float*)d_in[2];   // (NH,OBS,D)
    const float* a1   = (const float*)d_in[3];   // (NH,2D)
    const float* W2   = (const float*)d_in[4];   // (NH,HID,D)
    const float* a2   = (const float*)d_in[5];   // (NH,2D)
    float* out = (float*)d_out;

    float* ws = (float*)d_ws;
    const size_t nWhT_f = (size_t)Bc * NHc * Dc * Nc / 2;   // 786432
    const size_t nXh_f  = (size_t)Bc * Nc * HIDc / 2;       // 786432
    const size_t nAb_f  = (size_t)Nc * 16 * 2;              // 32768
    const size_t nW2T_f = 36864 / 2;                        // 18432
    const size_t nR     = (size_t)Bc * NHc * Nc;            // 24576
    _Float16* WhT = (_Float16*)ws;
    _Float16* xh  = (_Float16*)(ws + nWhT_f);
    unsigned long long* adjb = (unsigned long long*)(ws + nWhT_f + nXh_f);
    _Float16* W2T = (_Float16*)(ws + nWhT_f + nXh_f + nAb_f);
    float* si = ws + nWhT_f + nXh_f + nAb_f + nW2T_f;
    float* sj = si + nR;
    unsigned int* Menc = (unsigned int*)(sj + nR);   // 48 slots

    (void)hipMemsetAsync(Menc, 0, 48 * sizeof(unsigned int), stream);

    dim3 projGrid1(Nc / 32, Bc * NHc + 1);   // +1 y-slice: adj pack + W2 convert
    dim3 projGrid2(Nc / 32, Bc * NHc);

    // ----- Layer 1 -----
    proj1_kernel<<<projGrid1, 256, 0, stream>>>(
        h_in, W1, a1, WhT, si, sj, Menc, adj, adjb, W2, W2T);
    aggr_kernel<true, _Float16><<<1536, 256, 0, stream>>>(
        WhT, si, sj, Menc, adjb, xh);

    // ----- Layer 2 -----
    proj2_kernel<<<projGrid2, 256, 0, stream>>>(
        xh, W2T, a2, WhT, si, sj, Menc + 24);
    aggr_kernel<false, float><<<1536, 256, 0, stream>>>(
        WhT, si, sj, Menc + 24, adjb, out);
}